// Round 7
// baseline (1168.913 us; speedup 1.0000x reference)
//
#include <hip/hip_runtime.h>
#include <math.h>

#define NN 50000
#define EE 1600000
#define IND 300
#define KPAD 320
#define NL 3
#define NBLK 785
#define AGG_NB 12500

typedef unsigned short u16;
typedef __attribute__((ext_vector_type(8))) short short8;
typedef __attribute__((ext_vector_type(4))) float floatx4;

__device__ __forceinline__ float b2f(u16 u) {
  union { unsigned i; float f; } v; v.i = ((unsigned)u) << 16; return v.f;
}
__device__ __forceinline__ u16 f2b(float f) {
  union { unsigned i; float f; } v; v.f = f;
  unsigned b = v.i; b += 0x7fffu + ((b >> 16) & 1u);
  return (u16)(b >> 16);
}
__device__ __forceinline__ float sigf(float x) { return 1.0f / (1.0f + __expf(-x)); }

// ============================ CSR build ============================
__global__ void count_kernel(const int* __restrict__ dst, int* __restrict__ cnt) {
  int e = blockIdx.x * 256 + threadIdx.x;
  if (e < EE) atomicAdd(&cnt[dst[e]], 1);
}

__global__ __launch_bounds__(256) void scan1_kernel(const int* __restrict__ cnt,
                                                    int* __restrict__ rs,
                                                    int* __restrict__ bsum) {
  __shared__ int ws[4];
  const int t = threadIdx.x, l = t & 63, w = t >> 6;
  const int base = blockIdx.x * 2048 + t * 8;
  int v[8];
  int tot = 0;
  #pragma unroll
  for (int k = 0; k < 8; ++k) {
    int i = base + k;
    v[k] = (i < NN) ? cnt[i] : 0;
    tot += v[k];
  }
  int x = tot;
  #pragma unroll
  for (int off = 1; off < 64; off <<= 1) {
    int y = __shfl_up(x, off);
    if (l >= off) x += y;
  }
  if (l == 63) ws[w] = x;
  __syncthreads();
  int wpre = 0;
  for (int q = 0; q < w; ++q) wpre += ws[q];
  int run = wpre + (x - tot);
  #pragma unroll
  for (int k = 0; k < 8; ++k) {
    int i = base + k;
    if (i < NN) rs[i] = run;
    run += v[k];
  }
  if (t == 255) bsum[blockIdx.x] = wpre + x;
}

__global__ void scan2_kernel(int* __restrict__ bsum, int nb) {
  int l = threadIdx.x;
  int v = (l < nb) ? bsum[l] : 0;
  int x = v;
  #pragma unroll
  for (int off = 1; off < 64; off <<= 1) {
    int y = __shfl_up(x, off);
    if (l >= off) x += y;
  }
  if (l < nb) bsum[l] = x - v;
  if (l == 63) bsum[nb] = x;
}

__global__ void scan3_kernel(const int* __restrict__ bsum, int* __restrict__ rs, int nb) {
  int i = blockIdx.x * 256 + threadIdx.x;
  if (i < NN) rs[i] += bsum[i >> 11];
  if (i == 0) rs[NN] = bsum[nb];
}

__global__ void fill_kernel(const int* __restrict__ dst, const int* __restrict__ rs,
                            int* __restrict__ ncnt, const int* __restrict__ esrc,
                            const float* __restrict__ ew, int2* __restrict__ srcw) {
  int e = blockIdx.x * 256 + threadIdx.x;
  if (e < EE) {
    int d = dst[e];
    int p = atomicAdd(&ncnt[d], 1);
    int2 v;
    v.x = esrc[e];
    v.y = __float_as_int(ew[e]);
    srcw[rs[d] + p] = v;
  }
}

// ============================ role bucketing ============================
__global__ void role_count(const int* __restrict__ role, int* __restrict__ cnt3) {
  __shared__ int lc[3];
  if (threadIdx.x < 3) lc[threadIdx.x] = 0;
  __syncthreads();
  int i = blockIdx.x * 256 + threadIdx.x;
  if (i < NN) atomicAdd(&lc[role[i]], 1);
  __syncthreads();
  if (threadIdx.x < 3) atomicAdd(&cnt3[threadIdx.x], lc[threadIdx.x]);
}

__global__ void role_plan(const int* __restrict__ cnt3, int* __restrict__ pbase,
                          int* __restrict__ blkrole) {
  __shared__ int pb[4];
  if (threadIdx.x == 0) {
    pb[0] = 0;
    for (int b = 0; b < 3; ++b) pb[b + 1] = pb[b] + (((cnt3[b] + 63) >> 6) << 6);
    for (int b = 0; b < 4; ++b) pbase[b] = pb[b];
  }
  __syncthreads();
  for (int blk = threadIdx.x; blk < NBLK; blk += 256) {
    int m0 = blk * 64;
    int r = -1;
    for (int b = 0; b < 3; ++b)
      if (m0 >= pb[b] && m0 < pb[b + 1]) r = b;
    blkrole[blk] = r;
  }
}

__global__ void role_fill(const int* __restrict__ role, const int* __restrict__ pbase,
                          int* __restrict__ pos3, int* __restrict__ perm) {
  __shared__ int lcnt[3], lbase[3];
  int i = blockIdx.x * 256 + threadIdx.x;
  if (threadIdx.x < 3) lcnt[threadIdx.x] = 0;
  __syncthreads();
  int r = 0, lr = 0;
  bool valid = (i < NN);
  if (valid) {
    r = role[i];
    lr = atomicAdd(&lcnt[r], 1);
  }
  __syncthreads();
  if (threadIdx.x < 3) lbase[threadIdx.x] = atomicAdd(&pos3[threadIdx.x], lcnt[threadIdx.x]);
  __syncthreads();
  if (valid) perm[pbase[r] + lbase[r] + lr] = i;
}

// ============================ weight prep ============================
__global__ void xcast_kernel(const float* __restrict__ X, u16* __restrict__ Xb) {
  size_t i = (size_t)blockIdx.x * 256 + threadIdx.x;
  if (i >= (size_t)NN * KPAD) return;
  int r = (int)(i / KPAD), k = (int)(i % KPAD);
  Xb[i] = (k < IND) ? f2b(X[(size_t)r * IND + k]) : (u16)0;
}

__global__ void wt3_kernel(const float* __restrict__ Wq, const float* __restrict__ We,
                           const float* __restrict__ Wc, u16* __restrict__ Wqt,
                           u16* __restrict__ Wet, u16* __restrict__ Wct) {
  int n = blockIdx.x;
  int which = blockIdx.y;
  const float* W = (which == 0) ? Wq : (which == 1) ? We : Wc;
  u16* Wt = (which == 0) ? Wqt : (which == 1) ? Wet : Wct;
  for (int k = threadIdx.x; k < KPAD; k += 256)
    Wt[(size_t)n * KPAD + k] = (k < IND) ? f2b(W[(size_t)k * 256 + n]) : (u16)0;
}

__global__ void wallt_kernel(const float* __restrict__ Wv, const float* __restrict__ Wd,
                             u16* __restrict__ Wallt) {
  int i = blockIdx.x;
  int c = threadIdx.x;
  int hd = c >> 6, j = c & 63;
  const float* wv = &Wv[hd * (256 * 64) + i * 64];
  float s = 0.f;
  #pragma unroll
  for (int m = 0; m < 64; ++m) s = fmaf(wv[m], Wd[m * 64 + j], s);
  Wallt[(size_t)c * 256 + i] = f2b(s);
}

__global__ void ball_kernel(const float* __restrict__ bv, const float* __restrict__ Wd,
                            const float* __restrict__ bd, float* __restrict__ ball) {
  int c = threadIdx.x;
  int hd = c >> 6, j = c & 63;
  float s = bd[j];
  #pragma unroll
  for (int m = 0; m < 64; ++m) s = fmaf(bv[hd * 64 + m], Wd[m * 64 + j], s);
  ball[c] = s;
}

__global__ void wot_kernel(const float* __restrict__ Wo, u16* __restrict__ Wot) {
  int n = blockIdx.x;
  int k = threadIdx.x;
  Wot[(size_t)n * 256 + k] = f2b(Wo[(size_t)k * 256 + n]);
}

__global__ void castbf2_kernel(const float* __restrict__ s0, const float* __restrict__ s1,
                               u16* __restrict__ d0, u16* __restrict__ d1) {
  int i = blockIdx.x * 256 + threadIdx.x;
  const int n = 768 * 256;
  if (i < n) d0[i] = f2b(s0[i]);
  else if (i < 2 * n) d1[i - n] = f2b(s1[i - n]);
}

// ============================ 64-tile MFMA (proj) ============================
#define GEMM_PROLOG \
  __shared__ __align__(16) u16 As[64][72]; \
  __shared__ __align__(16) u16 Bs[64][72]; \
  const int t = threadIdx.x; \
  const int lane = t & 63; \
  const int wv_ = t >> 6; \
  const int wr = wv_ >> 1, wc = wv_ & 1; \
  const int l15 = lane & 15, l4 = lane >> 4; \
  const int srow = t >> 2; \
  const int scol = (t & 3) << 4;

#define STAGE_A(AG, ASTRIDE, VALID, ROWIDX, K0) { \
  int4 v0 = {0, 0, 0, 0}, v1 = {0, 0, 0, 0}; \
  if (VALID) { \
    const int4* p_ = (const int4*)&(AG)[(size_t)(ROWIDX) * (ASTRIDE) + (K0) + scol]; \
    v0 = p_[0]; v1 = p_[1]; \
  } \
  *(int4*)&As[srow][scol] = v0; \
  *(int4*)&As[srow][scol + 8] = v1; }

#define STAGE_B(BG, BSTRIDE, ROWIDX, K0) { \
  const int4* p_ = (const int4*)&(BG)[(size_t)(ROWIDX) * (BSTRIDE) + (K0) + scol]; \
  *(int4*)&Bs[srow][scol] = p_[0]; \
  *(int4*)&Bs[srow][scol + 8] = p_[1]; }

#define MFMA_STEP(ACC) { \
  _Pragma("unroll") \
  for (int kc = 0; kc < 2; ++kc) { \
    short8 a0_ = *(const short8*)&As[wr * 32 + 0 + l15][kc * 32 + l4 * 8]; \
    short8 a1_ = *(const short8*)&As[wr * 32 + 16 + l15][kc * 32 + l4 * 8]; \
    short8 b0_ = *(const short8*)&Bs[wc * 32 + 0 + l15][kc * 32 + l4 * 8]; \
    short8 b1_ = *(const short8*)&Bs[wc * 32 + 16 + l15][kc * 32 + l4 * 8]; \
    ACC[0][0] = __builtin_amdgcn_mfma_f32_16x16x32_bf16(a0_, b0_, ACC[0][0], 0, 0, 0); \
    ACC[0][1] = __builtin_amdgcn_mfma_f32_16x16x32_bf16(a0_, b1_, ACC[0][1], 0, 0, 0); \
    ACC[1][0] = __builtin_amdgcn_mfma_f32_16x16x32_bf16(a1_, b0_, ACC[1][0], 0, 0, 0); \
    ACC[1][1] = __builtin_amdgcn_mfma_f32_16x16x32_bf16(a1_, b1_, ACC[1][1], 0, 0, 0); \
  } }

// ============================ 128-tile MFMA (vgemm) ============================
#define GEMM128_PROLOG \
  __shared__ __align__(16) u16 As[128][72]; \
  __shared__ __align__(16) u16 Bs[128][72]; \
  const int t = threadIdx.x; \
  const int lane = t & 63; \
  const int wv_ = t >> 6; \
  const int qr = (wv_ >> 1) * 64, qc = (wv_ & 1) * 64; \
  const int l15 = lane & 15, l4 = lane >> 4; \
  const int srow = t >> 1; \
  const int scol = (t & 1) * 32;

#define STAGE128_A(AG, ASTRIDE, VALID, ROWIDX, K0) { \
  int4 v0 = {0,0,0,0}, v1 = {0,0,0,0}, v2 = {0,0,0,0}, v3 = {0,0,0,0}; \
  if (VALID) { \
    const int4* p_ = (const int4*)&(AG)[(size_t)(ROWIDX) * (ASTRIDE) + (K0) + scol]; \
    v0 = p_[0]; v1 = p_[1]; v2 = p_[2]; v3 = p_[3]; \
  } \
  *(int4*)&As[srow][scol] = v0; *(int4*)&As[srow][scol + 8] = v1; \
  *(int4*)&As[srow][scol + 16] = v2; *(int4*)&As[srow][scol + 24] = v3; }

#define STAGE128_B(BG, BSTRIDE, ROWIDX, K0) { \
  const int4* p_ = (const int4*)&(BG)[(size_t)(ROWIDX) * (BSTRIDE) + (K0) + scol]; \
  *(int4*)&Bs[srow][scol] = p_[0]; *(int4*)&Bs[srow][scol + 8] = p_[1]; \
  *(int4*)&Bs[srow][scol + 16] = p_[2]; *(int4*)&Bs[srow][scol + 24] = p_[3]; }

#define MFMA128_STEP(ACC) { \
  _Pragma("unroll") \
  for (int kc = 0; kc < 2; ++kc) { \
    short8 af_[4], bf_[4]; \
    _Pragma("unroll") \
    for (int m = 0; m < 4; ++m) af_[m] = *(const short8*)&As[qr + m * 16 + l15][kc * 32 + l4 * 8]; \
    _Pragma("unroll") \
    for (int n = 0; n < 4; ++n) bf_[n] = *(const short8*)&Bs[qc + n * 16 + l15][kc * 32 + l4 * 8]; \
    _Pragma("unroll") \
    for (int m = 0; m < 4; ++m) \
      _Pragma("unroll") \
      for (int n = 0; n < 4; ++n) \
        ACC[m][n] = __builtin_amdgcn_mfma_f32_16x16x32_bf16(af_[m], bf_[n], ACC[m][n], 0, 0, 0); \
  } }

// ============================ proj ============================
__global__ __launch_bounds__(256) void proj_mfma(
    const u16* __restrict__ Xb, const int* __restrict__ perm,
    const int* __restrict__ blkrole,
    const u16* __restrict__ Wqt, const u16* __restrict__ Wet, const u16* __restrict__ Wct,
    const float* __restrict__ bq, const float* __restrict__ be, const float* __restrict__ bc,
    u16* __restrict__ h, u16* __restrict__ pm) {
  const int brole = blkrole[blockIdx.y];
  if (brole < 0) return;
  GEMM_PROLOG
  const int m0 = blockIdx.y * 64;
  const int n0 = blockIdx.x * 64;
  const u16* Bt = (brole == 0) ? Wqt : (brole == 1) ? Wet : Wct;
  const float* bb = (brole == 0) ? bq : (brole == 1) ? be : bc;
  const int prow = perm[m0 + srow];
  floatx4 acc[2][2] = {};
  for (int k0 = 0; k0 < KPAD; k0 += 64) {
    STAGE_A(Xb, KPAD, prow >= 0, prow, k0)
    STAGE_B(Bt, KPAD, n0 + srow, k0)
    __syncthreads();
    MFMA_STEP(acc)
    __syncthreads();
  }
  #pragma unroll
  for (int m = 0; m < 2; ++m)
    #pragma unroll
    for (int reg = 0; reg < 4; ++reg) {
      int gr = m0 + wr * 32 + m * 16 + l4 * 4 + reg;
      int pr = perm[gr];
      if (pr >= 0) {
        #pragma unroll
        for (int n = 0; n < 2; ++n) {
          int c = n0 + wc * 32 + n * 16 + l15;
          float vo = fmaxf(acc[m][n][reg] + bb[c], 0.f);
          u16 ub = f2b(vo);
          h[(size_t)pr * 256 + c] = ub;
          pm[(size_t)pr * 256 + c] = ub;
        }
      }
    }
}

// ============================ V = h @ Wall + ball ============================
__global__ __launch_bounds__(256) void vgemm_mfma(
    const u16* __restrict__ A, const u16* __restrict__ Bt,
    const float* __restrict__ bias, u16* __restrict__ C) {
  GEMM128_PROLOG
  const int m0 = blockIdx.y * 128;
  const int n0 = blockIdx.x * 128;
  const int ar = m0 + srow;
  floatx4 acc[4][4] = {};
  for (int k0 = 0; k0 < 256; k0 += 64) {
    STAGE128_A(A, 256, ar < NN, ar, k0)
    STAGE128_B(Bt, 256, n0 + srow, k0)
    __syncthreads();
    MFMA128_STEP(acc)
    __syncthreads();
  }
  #pragma unroll
  for (int m = 0; m < 4; ++m)
    #pragma unroll
    for (int reg = 0; reg < 4; ++reg) {
      int gr = m0 + qr + m * 16 + l4 * 4 + reg;
      if (gr < NN) {
        #pragma unroll
        for (int n = 0; n < 4; ++n) {
          int c = n0 + qc + n * 16 + l15;
          C[(size_t)gr * 256 + c] = f2b(acc[m][n][reg] + bias[c]);
        }
      }
    }
}

// ============================ aggregation (column-sliced x2, ILP-4) ============================
__global__ __launch_bounds__(256) void agg_kernel(
    const int2* __restrict__ srcw, const int* __restrict__ rs,
    const u16* __restrict__ V, u16* __restrict__ comb) {
  int bid = blockIdx.x;
  int slice = (bid >= AGG_NB) ? 1 : 0;
  int nb = bid - slice * AGG_NB;
  int n = nb * 4 + (threadIdx.x >> 6);
  int l = threadIdx.x & 63;
  if (n >= NN) return;
  int s = rs[n], e = rs[n + 1];
  const size_t coff = (size_t)(slice << 7) + l * 2;
  float a0 = 0.f, a1 = 0.f, c0 = 0.f, c1 = 0.f;
  for (int base = s; base < e; base += 64) {
    int2 p = {0, 0};
    if (base + l < e) p = srcw[base + l];
    int cnt = min(64, e - base);
    int j = 0;
    for (; j + 4 <= cnt; j += 4) {
      int s0 = __shfl(p.x, j + 0), s1 = __shfl(p.x, j + 1);
      int s2 = __shfl(p.x, j + 2), s3 = __shfl(p.x, j + 3);
      float w0 = __int_as_float(__shfl(p.y, j + 0));
      float w1 = __int_as_float(__shfl(p.y, j + 1));
      float w2 = __int_as_float(__shfl(p.y, j + 2));
      float w3 = __int_as_float(__shfl(p.y, j + 3));
      ushort2 v0 = *(const ushort2*)&V[(size_t)s0 * 256 + coff];
      ushort2 v1 = *(const ushort2*)&V[(size_t)s1 * 256 + coff];
      ushort2 v2 = *(const ushort2*)&V[(size_t)s2 * 256 + coff];
      ushort2 v3 = *(const ushort2*)&V[(size_t)s3 * 256 + coff];
      a0 = fmaf(w0, b2f(v0.x), a0); a1 = fmaf(w0, b2f(v0.y), a1);
      c0 = fmaf(w1, b2f(v1.x), c0); c1 = fmaf(w1, b2f(v1.y), c1);
      a0 = fmaf(w2, b2f(v2.x), a0); a1 = fmaf(w2, b2f(v2.y), a1);
      c0 = fmaf(w3, b2f(v3.x), c0); c1 = fmaf(w3, b2f(v3.y), c1);
    }
    for (; j < cnt; ++j) {
      int src = __shfl(p.x, j);
      float w = __int_as_float(__shfl(p.y, j));
      ushort2 v = *(const ushort2*)&V[(size_t)src * 256 + coff];
      a0 = fmaf(w, b2f(v.x), a0); a1 = fmaf(w, b2f(v.y), a1);
    }
  }
  a0 += c0; a1 += c1;
  ushort2 o;
  o.x = f2b(a0); o.y = f2b(a1);
  *(ushort2*)&comb[(size_t)n * 256 + coff] = o;
}

// ============================ fused GRU (BK=32, 40KB LDS -> 4 blocks/CU) ============================
__global__ __launch_bounds__(256) void gru_mfma(
    const u16* __restrict__ comb, const u16* __restrict__ pmc,
    const u16* __restrict__ Wiht, const u16* __restrict__ Whht,
    const float* __restrict__ bih, const float* __restrict__ bhh,
    u16* __restrict__ pmn) {
  __shared__ __align__(16) u16 As[2][64][40];
  __shared__ __align__(16) u16 Bs[6][64][40];
  const int t = threadIdx.x;
  const int lane = t & 63;
  const int wv_ = t >> 6;
  const int wr = wv_ >> 1, wc = wv_ & 1;
  const int l15 = lane & 15, l4 = lane >> 4;
  const int srow = t >> 2;
  const int kq = (t & 3) << 3;  // 8 bf16 = one int4
  const int m0 = blockIdx.y * 64;
  const int cb = blockIdx.x;    // 64-col slice of hidden
  const int ar = m0 + srow;
  const bool av = ar < NN;
  floatx4 acc[6][2][2] = {};
  for (int k0 = 0; k0 < 256; k0 += 32) {
    {
      int4 v0 = {0, 0, 0, 0}, u0 = {0, 0, 0, 0};
      if (av) {
        v0 = *(const int4*)&comb[(size_t)ar * 256 + k0 + kq];
        u0 = *(const int4*)&pmc[(size_t)ar * 256 + k0 + kq];
      }
      *(int4*)&As[0][srow][kq] = v0;
      *(int4*)&As[1][srow][kq] = u0;
    }
    #pragma unroll
    for (int g = 0; g < 3; ++g) {
      size_t row = (size_t)(g * 256 + cb * 64 + srow);
      *(int4*)&Bs[g][srow][kq] = *(const int4*)&Wiht[row * 256 + k0 + kq];
      *(int4*)&Bs[3 + g][srow][kq] = *(const int4*)&Whht[row * 256 + k0 + kq];
    }
    __syncthreads();
    short8 a0f[2], a1f[2];
    #pragma unroll
    for (int m = 0; m < 2; ++m) {
      a0f[m] = *(const short8*)&As[0][wr * 32 + m * 16 + l15][l4 * 8];
      a1f[m] = *(const short8*)&As[1][wr * 32 + m * 16 + l15][l4 * 8];
    }
    #pragma unroll
    for (int g = 0; g < 3; ++g) {
      short8 b0 = *(const short8*)&Bs[g][wc * 32 + 0 + l15][l4 * 8];
      short8 b1 = *(const short8*)&Bs[g][wc * 32 + 16 + l15][l4 * 8];
      acc[g][0][0] = __builtin_amdgcn_mfma_f32_16x16x32_bf16(a0f[0], b0, acc[g][0][0], 0, 0, 0);
      acc[g][0][1] = __builtin_amdgcn_mfma_f32_16x16x32_bf16(a0f[0], b1, acc[g][0][1], 0, 0, 0);
      acc[g][1][0] = __builtin_amdgcn_mfma_f32_16x16x32_bf16(a0f[1], b0, acc[g][1][0], 0, 0, 0);
      acc[g][1][1] = __builtin_amdgcn_mfma_f32_16x16x32_bf16(a0f[1], b1, acc[g][1][1], 0, 0, 0);
    }
    #pragma unroll
    for (int g = 3; g < 6; ++g) {
      short8 b0 = *(const short8*)&Bs[g][wc * 32 + 0 + l15][l4 * 8];
      short8 b1 = *(const short8*)&Bs[g][wc * 32 + 16 + l15][l4 * 8];
      acc[g][0][0] = __builtin_amdgcn_mfma_f32_16x16x32_bf16(a1f[0], b0, acc[g][0][0], 0, 0, 0);
      acc[g][0][1] = __builtin_amdgcn_mfma_f32_16x16x32_bf16(a1f[0], b1, acc[g][0][1], 0, 0, 0);
      acc[g][1][0] = __builtin_amdgcn_mfma_f32_16x16x32_bf16(a1f[1], b0, acc[g][1][0], 0, 0, 0);
      acc[g][1][1] = __builtin_amdgcn_mfma_f32_16x16x32_bf16(a1f[1], b1, acc[g][1][1], 0, 0, 0);
    }
    __syncthreads();
  }
  #pragma unroll
  for (int m = 0; m < 2; ++m)
    #pragma unroll
    for (int reg = 0; reg < 4; ++reg) {
      int gr = m0 + wr * 32 + m * 16 + l4 * 4 + reg;
      if (gr < NN) {
        #pragma unroll
        for (int n = 0; n < 2; ++n) {
          int c = cb * 64 + wc * 32 + n * 16 + l15;
          float r = sigf(acc[0][m][n][reg] + acc[3][m][n][reg] + bih[c] + bhh[c]);
          float z = sigf(acc[1][m][n][reg] + acc[4][m][n][reg] + bih[256 + c] + bhh[256 + c]);
          float i_n = acc[2][m][n][reg] + bih[512 + c];
          float h_n = acc[5][m][n][reg] + bhh[512 + c];
          float nn2 = tanhf(i_n + r * h_n);
          float po = b2f(pmc[(size_t)gr * 256 + c]);
          pmn[(size_t)gr * 256 + c] = f2b((1.f - z) * nn2 + z * po);
        }
      }
    }
}

// ============================ fused Wo-GEMM + residual + LayerNorm ============================
// tile M=64 x N=256 (full row); wave w owns cols [w*64, w*64+64)
__global__ __launch_bounds__(256) void wo_ln_mfma(
    const u16* __restrict__ comb, const u16* __restrict__ Wot,
    const float* __restrict__ bo, const u16* __restrict__ h_in,
    const float* __restrict__ lnw, const float* __restrict__ lnb,
    u16* __restrict__ h_out, const u16* __restrict__ pm,
    float* __restrict__ out, int last) {
  __shared__ __align__(16) u16 As[64][72];
  __shared__ __align__(16) u16 Bs[256][72];
  __shared__ float2 red[64][4];
  const int t = threadIdx.x;
  const int lane = t & 63;
  const int w = t >> 6;
  const int l15 = lane & 15, l4 = lane >> 4;
  const int m0 = blockIdx.x * 64;
  const int arow = t >> 2;
  const int ascol = (t & 3) << 4;
  floatx4 acc[4][4] = {};
  for (int k0 = 0; k0 < 256; k0 += 64) {
    {
      int r = m0 + arow;
      int4 v0 = {0, 0, 0, 0}, v1 = {0, 0, 0, 0};
      if (r < NN) {
        const int4* p = (const int4*)&comb[(size_t)r * 256 + k0 + ascol];
        v0 = p[0]; v1 = p[1];
      }
      *(int4*)&As[arow][ascol] = v0;
      *(int4*)&As[arow][ascol + 8] = v1;
    }
    {
      const int4* p = (const int4*)&Wot[(size_t)t * 256 + k0];
      #pragma unroll
      for (int q = 0; q < 8; ++q) *(int4*)&Bs[t][q * 8] = p[q];
    }
    __syncthreads();
    #pragma unroll
    for (int kc = 0; kc < 2; ++kc) {
      short8 af[4], bf[4];
      #pragma unroll
      for (int m = 0; m < 4; ++m) af[m] = *(const short8*)&As[m * 16 + l15][kc * 32 + l4 * 8];
      #pragma unroll
      for (int n = 0; n < 4; ++n) bf[n] = *(const short8*)&Bs[w * 64 + n * 16 + l15][kc * 32 + l4 * 8];
      #pragma unroll
      for (int m = 0; m < 4; ++m)
        #pragma unroll
        for (int n = 0; n < 4; ++n)
          acc[m][n] = __builtin_amdgcn_mfma_f32_16x16x32_bf16(af[m], bf[n], acc[m][n], 0, 0, 0);
    }
    __syncthreads();
  }
  // v = acc + bo + h_in; per-row sums (s, s2) across 256 cols
  #pragma unroll
  for (int m = 0; m < 4; ++m)
    #pragma unroll
    for (int reg = 0; reg < 4; ++reg) {
      int rloc = m * 16 + l4 * 4 + reg;
      int gr = m0 + rloc;
      float s = 0.f, s2 = 0.f;
      #pragma unroll
      for (int n = 0; n < 4; ++n) {
        int c = w * 64 + n * 16 + l15;
        float hv = (gr < NN) ? b2f(h_in[(size_t)gr * 256 + c]) : 0.f;
        float v = acc[m][n][reg] + bo[c] + hv;
        acc[m][n][reg] = v;
        s += v;
        s2 = fmaf(v, v, s2);
      }
      #pragma unroll
      for (int off = 1; off < 16; off <<= 1) {
        s += __shfl_xor(s, off);
        s2 += __shfl_xor(s2, off);
      }
      if (l15 == 0) red[rloc][w] = make_float2(s, s2);
    }
  __syncthreads();
  #pragma unroll
  for (int m = 0; m < 4; ++m)
    #pragma unroll
    for (int reg = 0; reg < 4; ++reg) {
      int rloc = m * 16 + l4 * 4 + reg;
      int gr = m0 + rloc;
      float2 r0 = red[rloc][0], r1 = red[rloc][1], r2 = red[rloc][2], r3 = red[rloc][3];
      float tot = (r0.x + r1.x) + (r2.x + r3.x);
      float tot2 = (r0.y + r1.y) + (r2.y + r3.y);
      float mu = tot * (1.f / 256.f);
      float var = tot2 * (1.f / 256.f) - mu * mu;
      float inv = rsqrtf(fmaxf(var, 0.f) + 1e-5f);
      if (gr < NN) {
        #pragma unroll
        for (int n = 0; n < 4; ++n) {
          int c = w * 64 + n * 16 + l15;
          float lnv = (acc[m][n][reg] - mu) * inv * lnw[c] + lnb[c];
          if (last) {
            out[(size_t)gr * 256 + c] = b2f(f2b(lnv)) + b2f(pm[(size_t)gr * 256 + c]);
          } else {
            h_out[(size_t)gr * 256 + c] = f2b(lnv);
          }
        }
      }
    }
}

extern "C" void kernel_launch(void* const* d_in, const int* in_sizes, int n_in,
                              void* d_out, int out_size, void* d_ws, size_t ws_size,
                              hipStream_t stream) {
  const float* node_feats = (const float*)d_in[0];
  const int* role = (const int*)d_in[1];
  const int* esrc = (const int*)d_in[2];
  const int* edst = (const int*)d_in[3];
  const float* ew = (const float*)d_in[4];
  const float* Wq = (const float*)d_in[5];
  const float* bq = (const float*)d_in[6];
  const float* We = (const float*)d_in[7];
  const float* be = (const float*)d_in[8];
  const float* Wc = (const float*)d_in[9];
  const float* bc = (const float*)d_in[10];
  const float* Wv = (const float*)d_in[11];
  const float* bv = (const float*)d_in[12];
  const float* Wd = (const float*)d_in[13];
  const float* bd = (const float*)d_in[14];
  const float* Wo = (const float*)d_in[15];
  const float* bo = (const float*)d_in[16];
  const float* Wih = (const float*)d_in[17];
  const float* Whh = (const float*)d_in[18];
  const float* bih = (const float*)d_in[19];
  const float* bhh = (const float*)d_in[20];
  const float* lnw = (const float*)d_in[21];
  const float* lnb = (const float*)d_in[22];
  float* out = (float*)d_out;

  char* ws = (char*)d_ws;
  size_t off = 0;
  auto take = [&](size_t bytes) {
    char* p = ws + off;
    off = (off + bytes + 511) & ~(size_t)511;
    return p;
  };
  const size_t NC2 = (size_t)NN * 256 * 2;
  u16* Xb = (u16*)take((size_t)NN * KPAD * 2);
  u16* h = (u16*)take(NC2);
  u16* pm0 = (u16*)take(NC2);
  u16* pm1 = (u16*)take(NC2);
  u16* V = (u16*)take(NC2);
  u16* comb = (u16*)take(NC2);
  u16* Wqt = (u16*)take((size_t)256 * KPAD * 2);
  u16* Wet = (u16*)take((size_t)256 * KPAD * 2);
  u16* Wct = (u16*)take((size_t)256 * KPAD * 2);
  u16* Wallt = (u16*)take((size_t)256 * 256 * 2);
  u16* Wot = (u16*)take((size_t)256 * 256 * 2);
  u16* Wiht = (u16*)take((size_t)768 * 256 * 2);
  u16* Whht = (u16*)take((size_t)768 * 256 * 2);
  float* ball = (float*)take(256 * 4);
  int* cnt = (int*)take((size_t)NN * 4);
  int* rs = (int*)take((size_t)(NN + 1) * 4);
  int* ncnt = (int*)take((size_t)NN * 4);
  int2* srcw = (int2*)take((size_t)EE * 8);
  int* cnt3 = (int*)take(16);
  int* pos3 = (int*)take(16);
  int* pbase = (int*)take(16);
  int* blkrole = (int*)take((size_t)NBLK * 4);
  int* perm = (int*)take((size_t)NBLK * 64 * 4);
  int* bsum = (int*)take(64 * 4);

  const int NB_SCAN = (NN + 2047) / 2048;  // 25

  hipMemsetAsync(cnt, 0, (size_t)NN * 4, stream);
  hipMemsetAsync(ncnt, 0, (size_t)NN * 4, stream);
  hipMemsetAsync(cnt3, 0, 16, stream);
  hipMemsetAsync(pos3, 0, 16, stream);
  hipMemsetAsync(perm, 0xFF, (size_t)NBLK * 64 * 4, stream);

  count_kernel<<<(EE + 255) / 256, 256, 0, stream>>>(edst, cnt);
  scan1_kernel<<<NB_SCAN, 256, 0, stream>>>(cnt, rs, bsum);
  scan2_kernel<<<1, 64, 0, stream>>>(bsum, NB_SCAN);
  scan3_kernel<<<(NN + 255) / 256, 256, 0, stream>>>(bsum, rs, NB_SCAN);
  fill_kernel<<<(EE + 255) / 256, 256, 0, stream>>>(edst, rs, ncnt, esrc, ew, srcw);

  role_count<<<(NN + 255) / 256, 256, 0, stream>>>(role, cnt3);
  role_plan<<<1, 256, 0, stream>>>(cnt3, pbase, blkrole);
  role_fill<<<(NN + 255) / 256, 256, 0, stream>>>(role, pbase, pos3, perm);

  xcast_kernel<<<(int)(((size_t)NN * KPAD + 255) / 256), 256, 0, stream>>>(node_feats, Xb);
  wt3_kernel<<<dim3(256, 3), 256, 0, stream>>>(Wq, We, Wc, Wqt, Wet, Wct);
  wallt_kernel<<<256, 256, 0, stream>>>(Wv, Wd, Wallt);
  ball_kernel<<<1, 256, 0, stream>>>(bv, Wd, bd, ball);
  wot_kernel<<<256, 256, 0, stream>>>(Wo, Wot);
  castbf2_kernel<<<(2 * 768 * 256 + 255) / 256, 256, 0, stream>>>(Wih, Whh, Wiht, Whht);

  proj_mfma<<<dim3(4, NBLK), 256, 0, stream>>>(Xb, perm, blkrole, Wqt, Wet, Wct,
                                               bq, be, bc, h, pm0);

  u16* pmc = pm0;
  u16* pmn = pm1;
  const int MB128 = (NN + 127) / 128;  // 391
  const int MB64 = (NN + 63) / 64;     // 782
  for (int layer = 0; layer < NL; ++layer) {
    vgemm_mfma<<<dim3(2, MB128), 256, 0, stream>>>(h, Wallt, ball, V);
    agg_kernel<<<2 * AGG_NB, 256, 0, stream>>>(srcw, rs, V, comb);
    gru_mfma<<<dim3(4, MB64), 256, 0, stream>>>(comb, pmc, Wiht, Whht, bih, bhh, pmn);
    wo_ln_mfma<<<MB64, 256, 0, stream>>>(comb, Wot, bo, h,
                                         lnw + layer * 256, lnb + layer * 256,
                                         h, pmn, out, (layer == NL - 1) ? 1 : 0);
    u16* sw = pmc; pmc = pmn; pmn = sw;
  }
}

// Round 8
// 1090.590 us; speedup vs baseline: 1.0718x; 1.0718x over previous
//
#include <hip/hip_runtime.h>
#include <math.h>

#define NN 50000
#define EE 1600000
#define IND 300
#define KPAD 320
#define NL 3
#define NBLK 785
#define AGG_NB 12500

typedef unsigned short u16;
typedef __attribute__((ext_vector_type(8))) short short8;
typedef __attribute__((ext_vector_type(4))) float floatx4;

__device__ __forceinline__ float b2f(u16 u) {
  union { unsigned i; float f; } v; v.i = ((unsigned)u) << 16; return v.f;
}
__device__ __forceinline__ u16 f2b(float f) {
  union { unsigned i; float f; } v; v.f = f;
  unsigned b = v.i; b += 0x7fffu + ((b >> 16) & 1u);
  return (u16)(b >> 16);
}
__device__ __forceinline__ float sigf(float x) { return 1.0f / (1.0f + __expf(-x)); }

// ============================ CSR build ============================
__global__ void count_kernel(const int* __restrict__ dst, int* __restrict__ cnt) {
  int e = blockIdx.x * 256 + threadIdx.x;
  if (e < EE) atomicAdd(&cnt[dst[e]], 1);
}

__global__ __launch_bounds__(256) void scan1_kernel(const int* __restrict__ cnt,
                                                    int* __restrict__ rs,
                                                    int* __restrict__ bsum) {
  __shared__ int ws[4];
  const int t = threadIdx.x, l = t & 63, w = t >> 6;
  const int base = blockIdx.x * 2048 + t * 8;
  int v[8];
  int tot = 0;
  #pragma unroll
  for (int k = 0; k < 8; ++k) {
    int i = base + k;
    v[k] = (i < NN) ? cnt[i] : 0;
    tot += v[k];
  }
  int x = tot;
  #pragma unroll
  for (int off = 1; off < 64; off <<= 1) {
    int y = __shfl_up(x, off);
    if (l >= off) x += y;
  }
  if (l == 63) ws[w] = x;
  __syncthreads();
  int wpre = 0;
  for (int q = 0; q < w; ++q) wpre += ws[q];
  int run = wpre + (x - tot);
  #pragma unroll
  for (int k = 0; k < 8; ++k) {
    int i = base + k;
    if (i < NN) rs[i] = run;
    run += v[k];
  }
  if (t == 255) bsum[blockIdx.x] = wpre + x;
}

__global__ void scan2_kernel(int* __restrict__ bsum, int nb) {
  int l = threadIdx.x;
  int v = (l < nb) ? bsum[l] : 0;
  int x = v;
  #pragma unroll
  for (int off = 1; off < 64; off <<= 1) {
    int y = __shfl_up(x, off);
    if (l >= off) x += y;
  }
  if (l < nb) bsum[l] = x - v;
  if (l == 63) bsum[nb] = x;
}

__global__ void scan3_kernel(const int* __restrict__ bsum, int* __restrict__ rs, int nb) {
  int i = blockIdx.x * 256 + threadIdx.x;
  if (i < NN) rs[i] += bsum[i >> 11];
  if (i == 0) rs[NN] = bsum[nb];
}

__global__ void fill_kernel(const int* __restrict__ dst, const int* __restrict__ rs,
                            int* __restrict__ ncnt, const int* __restrict__ esrc,
                            const float* __restrict__ ew, int2* __restrict__ srcw) {
  int e = blockIdx.x * 256 + threadIdx.x;
  if (e < EE) {
    int d = dst[e];
    int p = atomicAdd(&ncnt[d], 1);
    int2 v;
    v.x = esrc[e];
    v.y = __float_as_int(ew[e]);
    srcw[rs[d] + p] = v;
  }
}

// ============================ role bucketing ============================
__global__ void role_count(const int* __restrict__ role, int* __restrict__ cnt3) {
  __shared__ int lc[3];
  if (threadIdx.x < 3) lc[threadIdx.x] = 0;
  __syncthreads();
  int i = blockIdx.x * 256 + threadIdx.x;
  if (i < NN) atomicAdd(&lc[role[i]], 1);
  __syncthreads();
  if (threadIdx.x < 3) atomicAdd(&cnt3[threadIdx.x], lc[threadIdx.x]);
}

__global__ void role_plan(const int* __restrict__ cnt3, int* __restrict__ pbase,
                          int* __restrict__ blkrole) {
  __shared__ int pb[4];
  if (threadIdx.x == 0) {
    pb[0] = 0;
    for (int b = 0; b < 3; ++b) pb[b + 1] = pb[b] + (((cnt3[b] + 63) >> 6) << 6);
    for (int b = 0; b < 4; ++b) pbase[b] = pb[b];
  }
  __syncthreads();
  for (int blk = threadIdx.x; blk < NBLK; blk += 256) {
    int m0 = blk * 64;
    int r = -1;
    for (int b = 0; b < 3; ++b)
      if (m0 >= pb[b] && m0 < pb[b + 1]) r = b;
    blkrole[blk] = r;
  }
}

__global__ void role_fill(const int* __restrict__ role, const int* __restrict__ pbase,
                          int* __restrict__ pos3, int* __restrict__ perm) {
  __shared__ int lcnt[3], lbase[3];
  int i = blockIdx.x * 256 + threadIdx.x;
  if (threadIdx.x < 3) lcnt[threadIdx.x] = 0;
  __syncthreads();
  int r = 0, lr = 0;
  bool valid = (i < NN);
  if (valid) {
    r = role[i];
    lr = atomicAdd(&lcnt[r], 1);
  }
  __syncthreads();
  if (threadIdx.x < 3) lbase[threadIdx.x] = atomicAdd(&pos3[threadIdx.x], lcnt[threadIdx.x]);
  __syncthreads();
  if (valid) perm[pbase[r] + lbase[r] + lr] = i;
}

// ============================ weight prep ============================
__global__ void xcast_kernel(const float* __restrict__ X, u16* __restrict__ Xb) {
  size_t i = (size_t)blockIdx.x * 256 + threadIdx.x;
  if (i >= (size_t)NN * KPAD) return;
  int r = (int)(i / KPAD), k = (int)(i % KPAD);
  Xb[i] = (k < IND) ? f2b(X[(size_t)r * IND + k]) : (u16)0;
}

__global__ void wt3_kernel(const float* __restrict__ Wq, const float* __restrict__ We,
                           const float* __restrict__ Wc, u16* __restrict__ Wqt,
                           u16* __restrict__ Wet, u16* __restrict__ Wct) {
  int n = blockIdx.x;
  int which = blockIdx.y;
  const float* W = (which == 0) ? Wq : (which == 1) ? We : Wc;
  u16* Wt = (which == 0) ? Wqt : (which == 1) ? Wet : Wct;
  for (int k = threadIdx.x; k < KPAD; k += 256)
    Wt[(size_t)n * KPAD + k] = (k < IND) ? f2b(W[(size_t)k * 256 + n]) : (u16)0;
}

__global__ void wallt_kernel(const float* __restrict__ Wv, const float* __restrict__ Wd,
                             u16* __restrict__ Wallt) {
  int i = blockIdx.x;
  int c = threadIdx.x;
  int hd = c >> 6, j = c & 63;
  const float* wv = &Wv[hd * (256 * 64) + i * 64];
  float s = 0.f;
  #pragma unroll
  for (int m = 0; m < 64; ++m) s = fmaf(wv[m], Wd[m * 64 + j], s);
  Wallt[(size_t)c * 256 + i] = f2b(s);
}

__global__ void ball_kernel(const float* __restrict__ bv, const float* __restrict__ Wd,
                            const float* __restrict__ bd, float* __restrict__ ball) {
  int c = threadIdx.x;
  int hd = c >> 6, j = c & 63;
  float s = bd[j];
  #pragma unroll
  for (int m = 0; m < 64; ++m) s = fmaf(bv[hd * 64 + m], Wd[m * 64 + j], s);
  ball[c] = s;
}

__global__ void wot_kernel(const float* __restrict__ Wo, u16* __restrict__ Wot) {
  int n = blockIdx.x;
  int k = threadIdx.x;
  Wot[(size_t)n * 256 + k] = f2b(Wo[(size_t)k * 256 + n]);
}

__global__ void castbf2_kernel(const float* __restrict__ s0, const float* __restrict__ s1,
                               u16* __restrict__ d0, u16* __restrict__ d1) {
  int i = blockIdx.x * 256 + threadIdx.x;
  const int n = 768 * 256;
  if (i < n) d0[i] = f2b(s0[i]);
  else if (i < 2 * n) d1[i - n] = f2b(s1[i - n]);
}

// Wrz[j][k] (j in [0,512), k in [0,512)): k<256 -> Wih[j][k], else Whh[j][k-256]
__global__ void wrz_kernel(const float* __restrict__ Wih, const float* __restrict__ Whh,
                           u16* __restrict__ Wrz) {
  int j = blockIdx.x;
  for (int k = threadIdx.x; k < 512; k += 256) {
    float v = (k < 256) ? Wih[(size_t)j * 256 + k] : Whh[(size_t)j * 256 + (k - 256)];
    Wrz[(size_t)j * 512 + k] = f2b(v);
  }
}

// ============================ 64-tile MFMA (proj) ============================
#define GEMM_PROLOG \
  __shared__ __align__(16) u16 As[64][72]; \
  __shared__ __align__(16) u16 Bs[64][72]; \
  const int t = threadIdx.x; \
  const int lane = t & 63; \
  const int wv_ = t >> 6; \
  const int wr = wv_ >> 1, wc = wv_ & 1; \
  const int l15 = lane & 15, l4 = lane >> 4; \
  const int srow = t >> 2; \
  const int scol = (t & 3) << 4;

#define STAGE_A(AG, ASTRIDE, VALID, ROWIDX, K0) { \
  int4 v0 = {0, 0, 0, 0}, v1 = {0, 0, 0, 0}; \
  if (VALID) { \
    const int4* p_ = (const int4*)&(AG)[(size_t)(ROWIDX) * (ASTRIDE) + (K0) + scol]; \
    v0 = p_[0]; v1 = p_[1]; \
  } \
  *(int4*)&As[srow][scol] = v0; \
  *(int4*)&As[srow][scol + 8] = v1; }

#define STAGE_B(BG, BSTRIDE, ROWIDX, K0) { \
  const int4* p_ = (const int4*)&(BG)[(size_t)(ROWIDX) * (BSTRIDE) + (K0) + scol]; \
  *(int4*)&Bs[srow][scol] = p_[0]; \
  *(int4*)&Bs[srow][scol + 8] = p_[1]; }

#define MFMA_STEP(ACC) { \
  _Pragma("unroll") \
  for (int kc = 0; kc < 2; ++kc) { \
    short8 a0_ = *(const short8*)&As[wr * 32 + 0 + l15][kc * 32 + l4 * 8]; \
    short8 a1_ = *(const short8*)&As[wr * 32 + 16 + l15][kc * 32 + l4 * 8]; \
    short8 b0_ = *(const short8*)&Bs[wc * 32 + 0 + l15][kc * 32 + l4 * 8]; \
    short8 b1_ = *(const short8*)&Bs[wc * 32 + 16 + l15][kc * 32 + l4 * 8]; \
    ACC[0][0] = __builtin_amdgcn_mfma_f32_16x16x32_bf16(a0_, b0_, ACC[0][0], 0, 0, 0); \
    ACC[0][1] = __builtin_amdgcn_mfma_f32_16x16x32_bf16(a0_, b1_, ACC[0][1], 0, 0, 0); \
    ACC[1][0] = __builtin_amdgcn_mfma_f32_16x16x32_bf16(a1_, b0_, ACC[1][0], 0, 0, 0); \
    ACC[1][1] = __builtin_amdgcn_mfma_f32_16x16x32_bf16(a1_, b1_, ACC[1][1], 0, 0, 0); \
  } }

// ============================ 128-tile MFMA (vgemm / wo) ============================
#define GEMM128_PROLOG \
  __shared__ __align__(16) u16 As[128][72]; \
  __shared__ __align__(16) u16 Bs[128][72]; \
  const int t = threadIdx.x; \
  const int lane = t & 63; \
  const int wv_ = t >> 6; \
  const int qr = (wv_ >> 1) * 64, qc = (wv_ & 1) * 64; \
  const int l15 = lane & 15, l4 = lane >> 4; \
  const int srow = t >> 1; \
  const int scol = (t & 1) * 32;

#define STAGE128_A(AG, ASTRIDE, VALID, ROWIDX, K0) { \
  int4 v0 = {0,0,0,0}, v1 = {0,0,0,0}, v2 = {0,0,0,0}, v3 = {0,0,0,0}; \
  if (VALID) { \
    const int4* p_ = (const int4*)&(AG)[(size_t)(ROWIDX) * (ASTRIDE) + (K0) + scol]; \
    v0 = p_[0]; v1 = p_[1]; v2 = p_[2]; v3 = p_[3]; \
  } \
  *(int4*)&As[srow][scol] = v0; *(int4*)&As[srow][scol + 8] = v1; \
  *(int4*)&As[srow][scol + 16] = v2; *(int4*)&As[srow][scol + 24] = v3; }

#define STAGE128_B(BG, BSTRIDE, ROWIDX, K0) { \
  const int4* p_ = (const int4*)&(BG)[(size_t)(ROWIDX) * (BSTRIDE) + (K0) + scol]; \
  *(int4*)&Bs[srow][scol] = p_[0]; *(int4*)&Bs[srow][scol + 8] = p_[1]; \
  *(int4*)&Bs[srow][scol + 16] = p_[2]; *(int4*)&Bs[srow][scol + 24] = p_[3]; }

#define MFMA128_STEP(ACC) { \
  _Pragma("unroll") \
  for (int kc = 0; kc < 2; ++kc) { \
    short8 af_[4], bf_[4]; \
    _Pragma("unroll") \
    for (int m = 0; m < 4; ++m) af_[m] = *(const short8*)&As[qr + m * 16 + l15][kc * 32 + l4 * 8]; \
    _Pragma("unroll") \
    for (int n = 0; n < 4; ++n) bf_[n] = *(const short8*)&Bs[qc + n * 16 + l15][kc * 32 + l4 * 8]; \
    _Pragma("unroll") \
    for (int m = 0; m < 4; ++m) \
      _Pragma("unroll") \
      for (int n = 0; n < 4; ++n) \
        ACC[m][n] = __builtin_amdgcn_mfma_f32_16x16x32_bf16(af_[m], bf_[n], ACC[m][n], 0, 0, 0); \
  } }

// ============================ proj ============================
__global__ __launch_bounds__(256) void proj_mfma(
    const u16* __restrict__ Xb, const int* __restrict__ perm,
    const int* __restrict__ blkrole,
    const u16* __restrict__ Wqt, const u16* __restrict__ Wet, const u16* __restrict__ Wct,
    const float* __restrict__ bq, const float* __restrict__ be, const float* __restrict__ bc,
    u16* __restrict__ h, u16* __restrict__ pm) {
  const int brole = blkrole[blockIdx.y];
  if (brole < 0) return;
  GEMM_PROLOG
  const int m0 = blockIdx.y * 64;
  const int n0 = blockIdx.x * 64;
  const u16* Bt = (brole == 0) ? Wqt : (brole == 1) ? Wet : Wct;
  const float* bb = (brole == 0) ? bq : (brole == 1) ? be : bc;
  const int prow = perm[m0 + srow];
  floatx4 acc[2][2] = {};
  for (int k0 = 0; k0 < KPAD; k0 += 64) {
    STAGE_A(Xb, KPAD, prow >= 0, prow, k0)
    STAGE_B(Bt, KPAD, n0 + srow, k0)
    __syncthreads();
    MFMA_STEP(acc)
    __syncthreads();
  }
  #pragma unroll
  for (int m = 0; m < 2; ++m)
    #pragma unroll
    for (int reg = 0; reg < 4; ++reg) {
      int gr = m0 + wr * 32 + m * 16 + l4 * 4 + reg;
      int pr = perm[gr];
      if (pr >= 0) {
        #pragma unroll
        for (int n = 0; n < 2; ++n) {
          int c = n0 + wc * 32 + n * 16 + l15;
          float vo = fmaxf(acc[m][n][reg] + bb[c], 0.f);
          u16 ub = f2b(vo);
          h[(size_t)pr * 256 + c] = ub;
          pm[(size_t)pr * 256 + c] = ub;
        }
      }
    }
}

// ============================ V = h @ Wall + ball ============================
__global__ __launch_bounds__(256) void vgemm_mfma(
    const u16* __restrict__ A, const u16* __restrict__ Bt,
    const float* __restrict__ bias, u16* __restrict__ C) {
  GEMM128_PROLOG
  const int m0 = blockIdx.y * 128;
  const int n0 = blockIdx.x * 128;
  const int ar = m0 + srow;
  floatx4 acc[4][4] = {};
  for (int k0 = 0; k0 < 256; k0 += 64) {
    STAGE128_A(A, 256, ar < NN, ar, k0)
    STAGE128_B(Bt, 256, n0 + srow, k0)
    __syncthreads();
    MFMA128_STEP(acc)
    __syncthreads();
  }
  #pragma unroll
  for (int m = 0; m < 4; ++m)
    #pragma unroll
    for (int reg = 0; reg < 4; ++reg) {
      int gr = m0 + qr + m * 16 + l4 * 4 + reg;
      if (gr < NN) {
        #pragma unroll
        for (int n = 0; n < 4; ++n) {
          int c = n0 + qc + n * 16 + l15;
          C[(size_t)gr * 256 + c] = f2b(acc[m][n][reg] + bias[c]);
        }
      }
    }
}

// ============================ aggregation (column-sliced x2, ILP-4) ============================
__global__ __launch_bounds__(256) void agg_kernel(
    const int2* __restrict__ srcw, const int* __restrict__ rs,
    const u16* __restrict__ V, u16* __restrict__ comb) {
  int bid = blockIdx.x;
  int slice = (bid >= AGG_NB) ? 1 : 0;
  int nb = bid - slice * AGG_NB;
  int n = nb * 4 + (threadIdx.x >> 6);
  int l = threadIdx.x & 63;
  if (n >= NN) return;
  int s = rs[n], e = rs[n + 1];
  const size_t coff = (size_t)(slice << 7) + l * 2;
  float a0 = 0.f, a1 = 0.f, c0 = 0.f, c1 = 0.f;
  for (int base = s; base < e; base += 64) {
    int2 p = {0, 0};
    if (base + l < e) p = srcw[base + l];
    int cnt = min(64, e - base);
    int j = 0;
    for (; j + 4 <= cnt; j += 4) {
      int s0 = __shfl(p.x, j + 0), s1 = __shfl(p.x, j + 1);
      int s2 = __shfl(p.x, j + 2), s3 = __shfl(p.x, j + 3);
      float w0 = __int_as_float(__shfl(p.y, j + 0));
      float w1 = __int_as_float(__shfl(p.y, j + 1));
      float w2 = __int_as_float(__shfl(p.y, j + 2));
      float w3 = __int_as_float(__shfl(p.y, j + 3));
      ushort2 v0 = *(const ushort2*)&V[(size_t)s0 * 256 + coff];
      ushort2 v1 = *(const ushort2*)&V[(size_t)s1 * 256 + coff];
      ushort2 v2 = *(const ushort2*)&V[(size_t)s2 * 256 + coff];
      ushort2 v3 = *(const ushort2*)&V[(size_t)s3 * 256 + coff];
      a0 = fmaf(w0, b2f(v0.x), a0); a1 = fmaf(w0, b2f(v0.y), a1);
      c0 = fmaf(w1, b2f(v1.x), c0); c1 = fmaf(w1, b2f(v1.y), c1);
      a0 = fmaf(w2, b2f(v2.x), a0); a1 = fmaf(w2, b2f(v2.y), a1);
      c0 = fmaf(w3, b2f(v3.x), c0); c1 = fmaf(w3, b2f(v3.y), c1);
    }
    for (; j < cnt; ++j) {
      int src = __shfl(p.x, j);
      float w = __int_as_float(__shfl(p.y, j));
      ushort2 v = *(const ushort2*)&V[(size_t)src * 256 + coff];
      a0 = fmaf(w, b2f(v.x), a0); a1 = fmaf(w, b2f(v.y), a1);
    }
  }
  a0 += c0; a1 += c1;
  ushort2 o;
  o.x = f2b(a0); o.y = f2b(a1);
  *(ushort2*)&comb[(size_t)n * 256 + coff] = o;
}

// ============================ fused GRU v2: concat-K, 4 LDS tiles ============================
// r,z via K=512 GEMM over [comb|pm] vs Wrz; n-gate i_n/h_n split across the 2 K-phases.
// LDS = 4 x 64x72 u16 = 36.9 KB -> 4 blocks/CU.
__global__ __launch_bounds__(256) void gru_mfma(
    const u16* __restrict__ comb, const u16* __restrict__ pmc,
    const u16* __restrict__ Wrz, const u16* __restrict__ Wiht, const u16* __restrict__ Whht,
    const float* __restrict__ bih, const float* __restrict__ bhh,
    u16* __restrict__ pmn) {
  __shared__ __align__(16) u16 As[64][72];
  __shared__ __align__(16) u16 Bs[3][64][72];
  const int t = threadIdx.x;
  const int lane = t & 63;
  const int wv_ = t >> 6;
  const int wr = wv_ >> 1, wc = wv_ & 1;
  const int l15 = lane & 15, l4 = lane >> 4;
  const int srow = t >> 2;
  const int scol = (t & 3) << 4;
  const int m0 = blockIdx.y * 64;
  const int cb = blockIdx.x;  // 64-col slice of hidden
  const int ar = m0 + srow;
  const bool av = ar < NN;
  floatx4 accR[2][2] = {}, accZ[2][2] = {}, accI[2][2] = {}, accH[2][2] = {};

#define GRU_PHASE(ASRC, BN, ACCN, KBASE) \
  for (int k0 = 0; k0 < 256; k0 += 64) { \
    { \
      int4 v0 = {0,0,0,0}, v1 = {0,0,0,0}; \
      if (av) { \
        const int4* p = (const int4*)&ASRC[(size_t)ar * 256 + k0 + scol]; \
        v0 = p[0]; v1 = p[1]; \
      } \
      *(int4*)&As[srow][scol] = v0; *(int4*)&As[srow][scol + 8] = v1; \
    } \
    { \
      const int4* pr = (const int4*)&Wrz[(size_t)(cb * 64 + srow) * 512 + (KBASE) + k0 + scol]; \
      *(int4*)&Bs[0][srow][scol] = pr[0]; *(int4*)&Bs[0][srow][scol + 8] = pr[1]; \
      const int4* pz = (const int4*)&Wrz[(size_t)(256 + cb * 64 + srow) * 512 + (KBASE) + k0 + scol]; \
      *(int4*)&Bs[1][srow][scol] = pz[0]; *(int4*)&Bs[1][srow][scol + 8] = pz[1]; \
      const int4* pn = (const int4*)&BN[(size_t)(512 + cb * 64 + srow) * 256 + k0 + scol]; \
      *(int4*)&Bs[2][srow][scol] = pn[0]; *(int4*)&Bs[2][srow][scol + 8] = pn[1]; \
    } \
    __syncthreads(); \
    _Pragma("unroll") \
    for (int kc = 0; kc < 2; ++kc) { \
      short8 a0 = *(const short8*)&As[wr * 32 + 0 + l15][kc * 32 + l4 * 8]; \
      short8 a1 = *(const short8*)&As[wr * 32 + 16 + l15][kc * 32 + l4 * 8]; \
      short8 br0 = *(const short8*)&Bs[0][wc * 32 + 0 + l15][kc * 32 + l4 * 8]; \
      short8 br1 = *(const short8*)&Bs[0][wc * 32 + 16 + l15][kc * 32 + l4 * 8]; \
      short8 bz0 = *(const short8*)&Bs[1][wc * 32 + 0 + l15][kc * 32 + l4 * 8]; \
      short8 bz1 = *(const short8*)&Bs[1][wc * 32 + 16 + l15][kc * 32 + l4 * 8]; \
      short8 bn0 = *(const short8*)&Bs[2][wc * 32 + 0 + l15][kc * 32 + l4 * 8]; \
      short8 bn1 = *(const short8*)&Bs[2][wc * 32 + 16 + l15][kc * 32 + l4 * 8]; \
      accR[0][0] = __builtin_amdgcn_mfma_f32_16x16x32_bf16(a0, br0, accR[0][0], 0, 0, 0); \
      accR[0][1] = __builtin_amdgcn_mfma_f32_16x16x32_bf16(a0, br1, accR[0][1], 0, 0, 0); \
      accR[1][0] = __builtin_amdgcn_mfma_f32_16x16x32_bf16(a1, br0, accR[1][0], 0, 0, 0); \
      accR[1][1] = __builtin_amdgcn_mfma_f32_16x16x32_bf16(a1, br1, accR[1][1], 0, 0, 0); \
      accZ[0][0] = __builtin_amdgcn_mfma_f32_16x16x32_bf16(a0, bz0, accZ[0][0], 0, 0, 0); \
      accZ[0][1] = __builtin_amdgcn_mfma_f32_16x16x32_bf16(a0, bz1, accZ[0][1], 0, 0, 0); \
      accZ[1][0] = __builtin_amdgcn_mfma_f32_16x16x32_bf16(a1, bz0, accZ[1][0], 0, 0, 0); \
      accZ[1][1] = __builtin_amdgcn_mfma_f32_16x16x32_bf16(a1, bz1, accZ[1][1], 0, 0, 0); \
      ACCN[0][0] = __builtin_amdgcn_mfma_f32_16x16x32_bf16(a0, bn0, ACCN[0][0], 0, 0, 0); \
      ACCN[0][1] = __builtin_amdgcn_mfma_f32_16x16x32_bf16(a0, bn1, ACCN[0][1], 0, 0, 0); \
      ACCN[1][0] = __builtin_amdgcn_mfma_f32_16x16x32_bf16(a1, bn0, ACCN[1][0], 0, 0, 0); \
      ACCN[1][1] = __builtin_amdgcn_mfma_f32_16x16x32_bf16(a1, bn1, ACCN[1][1], 0, 0, 0); \
    } \
    __syncthreads(); \
  }

  GRU_PHASE(comb, Wiht, accI, 0)
  GRU_PHASE(pmc, Whht, accH, 256)
#undef GRU_PHASE

  #pragma unroll
  for (int m = 0; m < 2; ++m)
    #pragma unroll
    for (int reg = 0; reg < 4; ++reg) {
      int gr = m0 + wr * 32 + m * 16 + l4 * 4 + reg;
      if (gr < NN) {
        #pragma unroll
        for (int n = 0; n < 2; ++n) {
          int c = cb * 64 + wc * 32 + n * 16 + l15;
          float r = sigf(accR[m][n][reg] + bih[c] + bhh[c]);
          float z = sigf(accZ[m][n][reg] + bih[256 + c] + bhh[256 + c]);
          float i_n = accI[m][n][reg] + bih[512 + c];
          float h_n = accH[m][n][reg] + bhh[512 + c];
          float nn2 = tanhf(i_n + r * h_n);
          float po = b2f(pmc[(size_t)gr * 256 + c]);
          pmn[(size_t)gr * 256 + c] = f2b((1.f - z) * nn2 + z * po);
        }
      }
    }
}

// ============================ tmp = comb @ Wo + bo + h ============================
__global__ __launch_bounds__(256) void wo_mfma(
    const u16* __restrict__ comb, const u16* __restrict__ Wot,
    const float* __restrict__ bo, const u16* __restrict__ h,
    u16* __restrict__ tmp) {
  GEMM128_PROLOG
  const int m0 = blockIdx.y * 128;
  const int n0 = blockIdx.x * 128;
  const int ar = m0 + srow;
  floatx4 acc[4][4] = {};
  for (int k0 = 0; k0 < 256; k0 += 64) {
    STAGE128_A(comb, 256, ar < NN, ar, k0)
    STAGE128_B(Wot, 256, n0 + srow, k0)
    __syncthreads();
    MFMA128_STEP(acc)
    __syncthreads();
  }
  #pragma unroll
  for (int m = 0; m < 4; ++m)
    #pragma unroll
    for (int reg = 0; reg < 4; ++reg) {
      int gr = m0 + qr + m * 16 + l4 * 4 + reg;
      if (gr < NN) {
        #pragma unroll
        for (int n = 0; n < 4; ++n) {
          int c = n0 + qc + n * 16 + l15;
          float v = acc[m][n][reg] + bo[c] + b2f(h[(size_t)gr * 256 + c]);
          tmp[(size_t)gr * 256 + c] = f2b(v);
        }
      }
    }
}

// ============================ LayerNorm ============================
__global__ __launch_bounds__(256) void ln_kernel(
    const u16* __restrict__ tmp, u16* __restrict__ h,
    const float* __restrict__ lnw, const float* __restrict__ lnb) {
  int n = blockIdx.x * 4 + (threadIdx.x >> 6);
  int l = threadIdx.x & 63;
  if (n >= NN) return;
  ushort4 v = *(const ushort4*)&tmp[(size_t)n * 256 + l * 4];
  float x0 = b2f(v.x), x1 = b2f(v.y), x2 = b2f(v.z), x3 = b2f(v.w);
  float s = x0 + x1 + x2 + x3;
  #pragma unroll
  for (int off = 1; off < 64; off <<= 1) s += __shfl_xor(s, off);
  float mu = s * (1.f / 256.f);
  float d0 = x0 - mu, d1 = x1 - mu, d2 = x2 - mu, d3 = x3 - mu;
  float vs = d0 * d0 + d1 * d1 + d2 * d2 + d3 * d3;
  #pragma unroll
  for (int off = 1; off < 64; off <<= 1) vs += __shfl_xor(vs, off);
  float inv = rsqrtf(vs * (1.f / 256.f) + 1e-5f);
  int c = l * 4;
  ushort4 o;
  o.x = f2b(d0 * inv * lnw[c + 0] + lnb[c + 0]);
  o.y = f2b(d1 * inv * lnw[c + 1] + lnb[c + 1]);
  o.z = f2b(d2 * inv * lnw[c + 2] + lnb[c + 2]);
  o.w = f2b(d3 * inv * lnw[c + 3] + lnb[c + 3]);
  *(ushort4*)&h[(size_t)n * 256 + c] = o;
}

__global__ __launch_bounds__(256) void ln_final_kernel(
    const u16* __restrict__ tmp, const u16* __restrict__ pm,
    const float* __restrict__ lnw, const float* __restrict__ lnb,
    float* __restrict__ out) {
  int n = blockIdx.x * 4 + (threadIdx.x >> 6);
  int l = threadIdx.x & 63;
  if (n >= NN) return;
  ushort4 v = *(const ushort4*)&tmp[(size_t)n * 256 + l * 4];
  float x0 = b2f(v.x), x1 = b2f(v.y), x2 = b2f(v.z), x3 = b2f(v.w);
  float s = x0 + x1 + x2 + x3;
  #pragma unroll
  for (int off = 1; off < 64; off <<= 1) s += __shfl_xor(s, off);
  float mu = s * (1.f / 256.f);
  float d0 = x0 - mu, d1 = x1 - mu, d2 = x2 - mu, d3 = x3 - mu;
  float vs = d0 * d0 + d1 * d1 + d2 * d2 + d3 * d3;
  #pragma unroll
  for (int off = 1; off < 64; off <<= 1) vs += __shfl_xor(vs, off);
  float inv = rsqrtf(vs * (1.f / 256.f) + 1e-5f);
  int c = l * 4;
  ushort4 pv = *(const ushort4*)&pm[(size_t)n * 256 + c];
  float4 o;
  o.x = b2f(f2b(d0 * inv * lnw[c + 0] + lnb[c + 0])) + b2f(pv.x);
  o.y = b2f(f2b(d1 * inv * lnw[c + 1] + lnb[c + 1])) + b2f(pv.y);
  o.z = b2f(f2b(d2 * inv * lnw[c + 2] + lnb[c + 2])) + b2f(pv.z);
  o.w = b2f(f2b(d3 * inv * lnw[c + 3] + lnb[c + 3])) + b2f(pv.w);
  *(float4*)&out[(size_t)n * 256 + c] = o;
}

extern "C" void kernel_launch(void* const* d_in, const int* in_sizes, int n_in,
                              void* d_out, int out_size, void* d_ws, size_t ws_size,
                              hipStream_t stream) {
  const float* node_feats = (const float*)d_in[0];
  const int* role = (const int*)d_in[1];
  const int* esrc = (const int*)d_in[2];
  const int* edst = (const int*)d_in[3];
  const float* ew = (const float*)d_in[4];
  const float* Wq = (const float*)d_in[5];
  const float* bq = (const float*)d_in[6];
  const float* We = (const float*)d_in[7];
  const float* be = (const float*)d_in[8];
  const float* Wc = (const float*)d_in[9];
  const float* bc = (const float*)d_in[10];
  const float* Wv = (const float*)d_in[11];
  const float* bv = (const float*)d_in[12];
  const float* Wd = (const float*)d_in[13];
  const float* bd = (const float*)d_in[14];
  const float* Wo = (const float*)d_in[15];
  const float* bo = (const float*)d_in[16];
  const float* Wih = (const float*)d_in[17];
  const float* Whh = (const float*)d_in[18];
  const float* bih = (const float*)d_in[19];
  const float* bhh = (const float*)d_in[20];
  const float* lnw = (const float*)d_in[21];
  const float* lnb = (const float*)d_in[22];
  float* out = (float*)d_out;

  char* ws = (char*)d_ws;
  size_t off = 0;
  auto take = [&](size_t bytes) {
    char* p = ws + off;
    off = (off + bytes + 511) & ~(size_t)511;
    return p;
  };
  const size_t NC2 = (size_t)NN * 256 * 2;
  u16* Xb = (u16*)take((size_t)NN * KPAD * 2);
  u16* h = (u16*)take(NC2);
  u16* pm0 = (u16*)take(NC2);
  u16* pm1 = (u16*)take(NC2);
  u16* V = (u16*)take(NC2);
  u16* comb = (u16*)take(NC2);
  u16* tmp = (u16*)take(NC2);
  u16* Wqt = (u16*)take((size_t)256 * KPAD * 2);
  u16* Wet = (u16*)take((size_t)256 * KPAD * 2);
  u16* Wct = (u16*)take((size_t)256 * KPAD * 2);
  u16* Wallt = (u16*)take((size_t)256 * 256 * 2);
  u16* Wot = (u16*)take((size_t)256 * 256 * 2);
  u16* Wiht = (u16*)take((size_t)768 * 256 * 2);
  u16* Whht = (u16*)take((size_t)768 * 256 * 2);
  u16* Wrz = (u16*)take((size_t)512 * 512 * 2);
  float* ball = (float*)take(256 * 4);
  int* cnt = (int*)take((size_t)NN * 4);
  int* rs = (int*)take((size_t)(NN + 1) * 4);
  int* ncnt = (int*)take((size_t)NN * 4);
  int2* srcw = (int2*)take((size_t)EE * 8);
  int* cnt3 = (int*)take(16);
  int* pos3 = (int*)take(16);
  int* pbase = (int*)take(16);
  int* blkrole = (int*)take((size_t)NBLK * 4);
  int* perm = (int*)take((size_t)NBLK * 64 * 4);
  int* bsum = (int*)take(64 * 4);

  const int NB_SCAN = (NN + 2047) / 2048;  // 25

  hipMemsetAsync(cnt, 0, (size_t)NN * 4, stream);
  hipMemsetAsync(ncnt, 0, (size_t)NN * 4, stream);
  hipMemsetAsync(cnt3, 0, 16, stream);
  hipMemsetAsync(pos3, 0, 16, stream);
  hipMemsetAsync(perm, 0xFF, (size_t)NBLK * 64 * 4, stream);

  count_kernel<<<(EE + 255) / 256, 256, 0, stream>>>(edst, cnt);
  scan1_kernel<<<NB_SCAN, 256, 0, stream>>>(cnt, rs, bsum);
  scan2_kernel<<<1, 64, 0, stream>>>(bsum, NB_SCAN);
  scan3_kernel<<<(NN + 255) / 256, 256, 0, stream>>>(bsum, rs, NB_SCAN);
  fill_kernel<<<(EE + 255) / 256, 256, 0, stream>>>(edst, rs, ncnt, esrc, ew, srcw);

  role_count<<<(NN + 255) / 256, 256, 0, stream>>>(role, cnt3);
  role_plan<<<1, 256, 0, stream>>>(cnt3, pbase, blkrole);
  role_fill<<<(NN + 255) / 256, 256, 0, stream>>>(role, pbase, pos3, perm);

  xcast_kernel<<<(int)(((size_t)NN * KPAD + 255) / 256), 256, 0, stream>>>(node_feats, Xb);
  wt3_kernel<<<dim3(256, 3), 256, 0, stream>>>(Wq, We, Wc, Wqt, Wet, Wct);
  wallt_kernel<<<256, 256, 0, stream>>>(Wv, Wd, Wallt);
  ball_kernel<<<1, 256, 0, stream>>>(bv, Wd, bd, ball);
  wot_kernel<<<256, 256, 0, stream>>>(Wo, Wot);
  castbf2_kernel<<<(2 * 768 * 256 + 255) / 256, 256, 0, stream>>>(Wih, Whh, Wiht, Whht);
  wrz_kernel<<<512, 256, 0, stream>>>(Wih, Whh, Wrz);

  proj_mfma<<<dim3(4, NBLK), 256, 0, stream>>>(Xb, perm, blkrole, Wqt, Wet, Wct,
                                               bq, be, bc, h, pm0);

  u16* pmc = pm0;
  u16* pmn = pm1;
  const int MB128 = (NN + 127) / 128;  // 391
  const int MB64 = (NN + 63) / 64;     // 782
  for (int layer = 0; layer < NL; ++layer) {
    vgemm_mfma<<<dim3(2, MB128), 256, 0, stream>>>(h, Wallt, ball, V);
    agg_kernel<<<2 * AGG_NB, 256, 0, stream>>>(srcw, rs, V, comb);
    gru_mfma<<<dim3(4, MB64), 256, 0, stream>>>(comb, pmc, Wrz, Wiht, Whht, bih, bhh, pmn);
    wo_mfma<<<dim3(2, MB128), 256, 0, stream>>>(comb, Wot, bo, h, tmp);
    if (layer < NL - 1) {
      ln_kernel<<<(NN + 3) / 4, 256, 0, stream>>>(tmp, h, lnw + layer * 256, lnb + layer * 256);
    } else {
      ln_final_kernel<<<(NN + 3) / 4, 256, 0, stream>>>(tmp, pmn, lnw + layer * 256,
                                                        lnb + layer * 256, out);
    }
    u16* sw = pmc; pmc = pmn; pmn = sw;
  }
}